// Round 2
// baseline (19082.669 us; speedup 1.0000x reference)
//
#include <hip/hip_runtime.h>
#include <hip/hip_bf16.h>
#include <stdint.h>

#define B_ 128
#define T_ 256
#define S_ 256
#define I_ 512
#define H_ 512

typedef __attribute__((ext_vector_type(8))) short short8;
typedef __attribute__((ext_vector_type(4))) float f32x4;
typedef unsigned short ushort_t;

__device__ __forceinline__ float bf2f(ushort_t u){
  union{ unsigned int i; float f;} v; v.i = ((unsigned int)u)<<16; return v.f;
}
__device__ __forceinline__ ushort_t f2bf(float f){
  union{ unsigned int i; float f;} v; v.f=f;
  unsigned int x=v.i; unsigned int r = x + 0x7fffu + ((x>>16)&1u);
  return (ushort_t)(r>>16);
}
__device__ __forceinline__ float sigm(float x){ return 1.f/(1.f + __expf(-x)); }
__device__ __forceinline__ float tanh_s(float x){
  float a = fabsf(x);
  float e = __expf(-2.f*a);
  float t = (1.f - e)/(1.f + e);
  return x < 0.f ? -t : t;
}

__device__ __forceinline__ f32x4 MFMA16(short8 a, short8 b, f32x4 c){
  typedef __attribute__((ext_vector_type(8))) __bf16 bf16x8;
  return __builtin_amdgcn_mfma_f32_16x16x32_bf16(
      __builtin_bit_cast(bf16x8, a), __builtin_bit_cast(bf16x8, b), c, 0, 0, 0);
}

// ---------------- converts / init ----------------

__global__ void k_cvt_bf16(const float* __restrict__ src, ushort_t* __restrict__ dst, int n){
  int i = (blockIdx.x*blockDim.x + threadIdx.x)*4;
  int stride = gridDim.x*blockDim.x*4;
  for (; i < n; i += stride){
    float4 v = *(const float4*)(src + i);
    ushort4 o; o.x=f2bf(v.x); o.y=f2bf(v.y); o.z=f2bf(v.z); o.w=f2bf(v.w);
    *(ushort4*)(dst + i) = o;
  }
}

// ctx[s][b][h] f32 -> ctxb[b][s][h] bf16
__global__ void k_relayout_ctx(const float* __restrict__ ctx, ushort_t* __restrict__ ctxb){
  int s = blockIdx.x >> 7;   // 0..255
  int b = blockIdx.x & 127;  // 0..127
  int h4 = threadIdx.x * 4;  // 128 threads
  float4 v = *(const float4*)(ctx + ((size_t)s*128 + b)*512 + h4);
  ushort4 o; o.x=f2bf(v.x); o.y=f2bf(v.y); o.z=f2bf(v.z); o.w=f2bf(v.w);
  *(ushort4*)(ctxb + ((size_t)b*256 + s)*512 + h4) = o;
}

__global__ void k_init_state(const float* __restrict__ h0, const float* __restrict__ c0,
                             ushort_t* __restrict__ hb, float* __restrict__ cyb){
  int i = blockIdx.x*blockDim.x + threadIdx.x; // 65536 total
  hb[i] = f2bf(h0[i]);
  cyb[i] = c0[i];
}

__global__ void k_zero_bar(int* f){
  if (threadIdx.x < 257) f[threadIdx.x] = 0;
}

// ---------------- big precompute GEMM (Xg) ----------------
// C[M,N] = A[M,K] @ B[N,K]^T (+ bias0[n]+bias1[n]), A,B fp32 in, C bf16 out.
template<int BIAS>
__global__ __launch_bounds__(256) void k_gemm_bt(
    const float* __restrict__ A, const float* __restrict__ Bm,
    ushort_t* __restrict__ C, int M, int N, int K,
    const float* __restrict__ bias0, const float* __restrict__ bias1){
  __shared__ ushort_t Asm[128][40];
  __shared__ ushort_t Bsm[128][40];
  const int tid = threadIdx.x;
  const int mBase = blockIdx.x*128, nBase = blockIdx.y*128;
  const int l = tid & 63, wv = tid >> 6;
  const int wm = (wv>>1)*64, wn = (wv&1)*64;
  const int lr = l & 15, lq = l >> 4;
  const int srow = tid >> 1, scol = (tid & 1)*16;
  const float* Ap = A + (size_t)(mBase + srow)*K + scol;
  const float* Bp = Bm + (size_t)(nBase + srow)*K + scol;

  f32x4 acc[4][4];
  #pragma unroll
  for (int i=0;i<4;i++)
    #pragma unroll
    for (int j=0;j<4;j++) acc[i][j] = (f32x4)0.f;

  for (int k0 = 0; k0 < K; k0 += 32){
    float4 a0 = *(const float4*)(Ap + k0);
    float4 a1 = *(const float4*)(Ap + k0 + 4);
    float4 a2 = *(const float4*)(Ap + k0 + 8);
    float4 a3 = *(const float4*)(Ap + k0 + 12);
    float4 b0 = *(const float4*)(Bp + k0);
    float4 b1 = *(const float4*)(Bp + k0 + 4);
    float4 b2 = *(const float4*)(Bp + k0 + 8);
    float4 b3 = *(const float4*)(Bp + k0 + 12);
    __syncthreads();
    {
      ushort4 w;
      w.x=f2bf(a0.x); w.y=f2bf(a0.y); w.z=f2bf(a0.z); w.w=f2bf(a0.w);
      *(ushort4*)&Asm[srow][scol+0]  = w;
      w.x=f2bf(a1.x); w.y=f2bf(a1.y); w.z=f2bf(a1.z); w.w=f2bf(a1.w);
      *(ushort4*)&Asm[srow][scol+4]  = w;
      w.x=f2bf(a2.x); w.y=f2bf(a2.y); w.z=f2bf(a2.z); w.w=f2bf(a2.w);
      *(ushort4*)&Asm[srow][scol+8]  = w;
      w.x=f2bf(a3.x); w.y=f2bf(a3.y); w.z=f2bf(a3.z); w.w=f2bf(a3.w);
      *(ushort4*)&Asm[srow][scol+12] = w;
      w.x=f2bf(b0.x); w.y=f2bf(b0.y); w.z=f2bf(b0.z); w.w=f2bf(b0.w);
      *(ushort4*)&Bsm[srow][scol+0]  = w;
      w.x=f2bf(b1.x); w.y=f2bf(b1.y); w.z=f2bf(b1.z); w.w=f2bf(b1.w);
      *(ushort4*)&Bsm[srow][scol+4]  = w;
      w.x=f2bf(b2.x); w.y=f2bf(b2.y); w.z=f2bf(b2.z); w.w=f2bf(b2.w);
      *(ushort4*)&Bsm[srow][scol+8]  = w;
      w.x=f2bf(b3.x); w.y=f2bf(b3.y); w.z=f2bf(b3.z); w.w=f2bf(b3.w);
      *(ushort4*)&Bsm[srow][scol+12] = w;
    }
    __syncthreads();
    short8 aF[4], bF[4];
    #pragma unroll
    for (int i=0;i<4;i++) aF[i] = *(const short8*)&Asm[wm + i*16 + lr][lq*8];
    #pragma unroll
    for (int j=0;j<4;j++) bF[j] = *(const short8*)&Bsm[wn + j*16 + lr][lq*8];
    #pragma unroll
    for (int i=0;i<4;i++)
      #pragma unroll
      for (int j=0;j<4;j++)
        acc[i][j] = MFMA16(aF[i], bF[j], acc[i][j]);
  }

  #pragma unroll
  for (int j=0;j<4;j++){
    int col = nBase + wn + j*16 + lr;
    float bsum = 0.f;
    if (BIAS) bsum = bias0[col] + bias1[col];
    #pragma unroll
    for (int i=0;i<4;i++){
      int row0 = mBase + wm + i*16 + lq*4;
      #pragma unroll
      for (int r=0;r<4;r++){
        C[(size_t)(row0+r)*N + col] = f2bf(acc[i][j][r] + bsum);
      }
    }
  }
}

// ---------------- grid barrier ----------------

__device__ __forceinline__ void gbar(int* flags, int* go, int gen){
  __syncthreads();
  if (threadIdx.x == 0){
    __threadfence();   // release: make this block's writes visible device-wide
    __hip_atomic_store(&flags[blockIdx.x], gen, __ATOMIC_RELAXED, __HIP_MEMORY_SCOPE_AGENT);
  }
  if (blockIdx.x == 0){
    if (threadIdx.x < 256){
      while (__hip_atomic_load(&flags[threadIdx.x], __ATOMIC_RELAXED, __HIP_MEMORY_SCOPE_AGENT) < gen)
        __builtin_amdgcn_s_sleep(2);
    }
    __syncthreads();
    if (threadIdx.x == 0){
      __threadfence();  // acquire for block0 + release of go
      __hip_atomic_store(go, gen, __ATOMIC_RELAXED, __HIP_MEMORY_SCOPE_AGENT);
    }
  } else {
    if (threadIdx.x == 0){
      while (__hip_atomic_load(go, __ATOMIC_RELAXED, __HIP_MEMORY_SCOPE_AGENT) < gen)
        __builtin_amdgcn_s_sleep(2);
      __threadfence();  // acquire: invalidate stale cached data
    }
  }
  __syncthreads();
}

// ---------------- persistent recurrence kernel ----------------
// 256 blocks x 512 threads (1 block/CU co-resident), whole T loop inside.

__global__ __launch_bounds__(512) void k_persist(
    const ushort_t* __restrict__ Xg, const ushort_t* __restrict__ ctxb,
    const ushort_t* __restrict__ Whb, const ushort_t* __restrict__ Woutb,
    const ushort_t* __restrict__ Winb,
    ushort_t* hb, ushort_t* hyb, ushort_t* wcb, ushort_t* targb,
    float* cyb, float* out, float* hf, float* cf,
    int* bar_flags, int* bar_go)
{
  __shared__ union {
    float red[8][256];                 // MFMA K-split reduce (8 KB)
    struct {
      ushort_t st[64][256];            // staged ctx half-tile (32 KB)
      float sc[64];
      float ps[64];
      float2 accs[512];                // wc partial accumulators (4 KB)
    } p3;
  } sh;

  const int pbid = blockIdx.x;
  const int tid = threadIdx.x;
  const int l = tid & 63, wv = tid >> 6;     // 8 waves
  const int lr = l & 15, lq = l >> 4;
  int gen = 0;

  for (int t = 0; t < T_; ++t){
    // ======== P1: gates = Xg[:,t,:] + h @ Wh^T ; LSTM pointwise ========
    {
      const int bm = pbid >> 5, hc = pbid & 31;   // 8 b-tiles x 32 h-chunks
      const int gate = wv & 3, khalf = wv >> 2;   // 4 gates x K-split-2
      f32x4 acc = (f32x4)0.f;
      const ushort_t* ap = hb + (bm*16 + lr)*512 + khalf*256 + lq*8;
      const ushort_t* bp = Whb + (size_t)(gate*512 + hc*16 + lr)*512 + khalf*256 + lq*8;
      #pragma unroll
      for (int kk = 0; kk < 8; ++kk){
        short8 aF = *(const short8*)(ap + kk*32);
        short8 bF = *(const short8*)(bp + kk*32);
        acc = MFMA16(aF, bF, acc);
      }
      #pragma unroll
      for (int r = 0; r < 4; ++r) sh.red[wv][(lq*4 + r)*16 + lr] = acc[r];
      __syncthreads();
      if (tid < 256){
        const int b = bm*16 + (tid >> 4), h = hc*16 + (tid & 15);
        const ushort_t* xg = Xg + ((size_t)b*T_ + t)*2048 + h;
        float gi  = sh.red[0][tid] + sh.red[4][tid] + bf2f(xg[0]);
        float gf  = sh.red[1][tid] + sh.red[5][tid] + bf2f(xg[512]);
        float gg  = sh.red[2][tid] + sh.red[6][tid] + bf2f(xg[1024]);
        float go_ = sh.red[3][tid] + sh.red[7][tid] + bf2f(xg[1536]);
        float co = cyb[b*512 + h];
        float cn = sigm(gf)*co + sigm(gi)*tanh_s(gg);
        float hn = sigm(go_)*tanh_s(cn);
        cyb[b*512 + h] = cn;
        hyb[b*512 + h] = f2bf(hn);
        if (t == T_-1) cf[b*512 + h] = cn;
      }
    }
    gbar(bar_flags, bar_go, ++gen);

    // ======== P2: target = hy @ W_in^T ========
    {
      const int bm = pbid >> 5, nc = pbid & 31;
      f32x4 acc = (f32x4)0.f;
      const ushort_t* ap = hyb + (bm*16 + lr)*512 + lq*8;
      const ushort_t* bp = Winb + (size_t)(nc*16 + lr)*512 + lq*8;
      #pragma unroll
      for (int kk = 0; kk < 2; ++kk){
        int k = wv*2 + kk;                       // K-split-8 over waves
        short8 aF = *(const short8*)(ap + k*32);
        short8 bF = *(const short8*)(bp + k*32);
        acc = MFMA16(aF, bF, acc);
      }
      #pragma unroll
      for (int r = 0; r < 4; ++r) sh.red[wv][(lq*4 + r)*16 + lr] = acc[r];
      __syncthreads();
      if (tid < 256){
        float s = 0.f;
        #pragma unroll
        for (int w = 0; w < 8; ++w) s += sh.red[w][tid];
        const int b = bm*16 + (tid >> 4), n = nc*16 + (tid & 15);
        targb[b*512 + n] = f2bf(s);
      }
    }
    gbar(bar_flags, bar_go, ++gen);

    // ======== P3: attention (flash-style, ctx read once) ========
    {
      const int b = pbid & 127, half = pbid >> 7;  // 2 blocks per batch row
      float tv[8];
      {
        short8 tvv = *(const short8*)(targb + b*512 + l*8);
        #pragma unroll
        for (int e = 0; e < 8; ++e) tv[e] = bf2f((ushort_t)tvv[e]);
      }
      float m_run = -3.0e38f, l_run = 0.f;
      float2 acc2 = make_float2(0.f, 0.f);
      const int q = tid & 127, spq = tid >> 7;     // h-pair, s-quarter

      for (int tile = 0; tile < 4; ++tile){
        const int s0 = tile*64;
        // dot + stage: 8 waves x 8 rows
        #pragma unroll 2
        for (int i = 0; i < 8; ++i){
          const int srow = wv*8 + i;
          short8 cv = *(const short8*)(ctxb + ((size_t)b*256 + s0 + srow)*512 + l*8);
          float d = 0.f;
          #pragma unroll
          for (int e = 0; e < 8; ++e) d += bf2f((ushort_t)cv[e]) * tv[e];
          #pragma unroll
          for (int off = 32; off; off >>= 1) d += __shfl_xor(d, off);
          if ((l >> 5) == half)
            *(short8*)&sh.p3.st[srow][(l & 31)*8] = cv;
          if (l == 0) sh.p3.sc[srow] = d;
        }
        __syncthreads();
        // online softmax update (redundant per wave, consistent)
        {
          float sv = sh.p3.sc[l];
          float tmax = sv;
          #pragma unroll
          for (int off = 32; off; off >>= 1) tmax = fmaxf(tmax, __shfl_xor(tmax, off));
          float m_new = fmaxf(m_run, tmax);
          float alpha = __expf(m_run - m_new);
          float p = __expf(sv - m_new);
          float psum = p;
          #pragma unroll
          for (int off = 32; off; off >>= 1) psum += __shfl_xor(psum, off);
          l_run = l_run*alpha + psum;
          m_run = m_new;
          if (wv == 0) sh.p3.ps[l] = p;
          acc2.x *= alpha; acc2.y *= alpha;
        }
        __syncthreads();
        // wc partial update from LDS
        #pragma unroll 4
        for (int j = 0; j < 16; ++j){
          int srow = spq*16 + j;
          float pw = sh.p3.ps[srow];
          uint32_t uv = *(const uint32_t*)&sh.p3.st[srow][q*2];
          acc2.x += pw * bf2f((ushort_t)(uv & 0xffffu));
          acc2.y += pw * bf2f((ushort_t)(uv >> 16));
        }
        __syncthreads();
      }
      sh.p3.accs[tid] = acc2;
      __syncthreads();
      if (tid < 128){
        float inv = 1.f / l_run;
        float2 a0 = sh.p3.accs[tid],       a1 = sh.p3.accs[tid + 128];
        float2 a2 = sh.p3.accs[tid + 256], a3 = sh.p3.accs[tid + 384];
        ushort2 w;
        w.x = f2bf((a0.x + a1.x + a2.x + a3.x)*inv);
        w.y = f2bf((a0.y + a1.y + a2.y + a3.y)*inv);
        *(ushort2*)(wcb + b*512 + half*256 + tid*2) = w;
      }
    }
    gbar(bar_flags, bar_go, ++gen);

    // ======== P4: h_tilde = tanh([wc|hy] @ W_out^T) ========
    {
      const int bm = pbid >> 5, nc = pbid & 31;
      f32x4 acc = (f32x4)0.f;
      const ushort_t* ap = (wv < 4 ? wcb : hyb) + (bm*16 + lr)*512 + (wv & 3)*128 + lq*8;
      const ushort_t* bp = Woutb + (size_t)(nc*16 + lr)*1024 + wv*128 + lq*8;
      #pragma unroll
      for (int kk = 0; kk < 4; ++kk){
        short8 aF = *(const short8*)(ap + kk*32);
        short8 bF = *(const short8*)(bp + kk*32);
        acc = MFMA16(aF, bF, acc);
      }
      #pragma unroll
      for (int r = 0; r < 4; ++r) sh.red[wv][(lq*4 + r)*16 + lr] = acc[r];
      __syncthreads();
      if (tid < 256){
        float s = 0.f;
        #pragma unroll
        for (int w = 0; w < 8; ++w) s += sh.red[w][tid];
        float v = tanh_s(s);
        const int b = bm*16 + (tid >> 4), n = nc*16 + (tid & 15);
        out[((size_t)b*T_ + t)*512 + n] = v;
        hb[b*512 + n] = f2bf(v);
        if (t == T_-1) hf[b*512 + n] = v;
      }
    }
    gbar(bar_flags, bar_go, ++gen);
  }
}

// ---------------- host ----------------

extern "C" void kernel_launch(void* const* d_in, const int* in_sizes, int n_in,
                              void* d_out, int out_size, void* d_ws, size_t ws_size,
                              hipStream_t stream){
  const float* x    = (const float*)d_in[0];
  const float* h0   = (const float*)d_in[1];
  const float* c0   = (const float*)d_in[2];
  const float* ctx  = (const float*)d_in[3];
  const float* Wi   = (const float*)d_in[4];
  const float* bi   = (const float*)d_in[5];
  const float* Wh   = (const float*)d_in[6];
  const float* bh   = (const float*)d_in[7];
  const float* Win  = (const float*)d_in[8];
  const float* Wout = (const float*)d_in[9];

  char* ws = (char*)d_ws;
  ushort_t* Xg    = (ushort_t*)(ws);                 // 134217728 B
  ushort_t* ctxb  = (ushort_t*)(ws + 134217728);     //  33554432 B
  ushort_t* Whb   = (ushort_t*)(ws + 167772160);     //   2097152 B
  ushort_t* Woutb = (ushort_t*)(ws + 169869312);     //   1048576 B
  ushort_t* Winb  = (ushort_t*)(ws + 170917888);     //    524288 B
  ushort_t* targb = (ushort_t*)(ws + 171442176);     //    131072 B
  ushort_t* hb    = (ushort_t*)(ws + 171573248);     //    131072 B
  ushort_t* hyb   = (ushort_t*)(ws + 171704320);     //    131072 B
  ushort_t* wcb   = (ushort_t*)(ws + 171835392);     //    131072 B
  float*    cyb   = (float*)   (ws + 171966464);     //    262144 B
  int*      barm  = (int*)     (ws + 172228608);     //      1024 B

  float* out = (float*)d_out;
  float* hf  = out + (size_t)B_*T_*H_;
  float* cf  = hf + (size_t)B_*H_;

  // precompute / converts
  k_relayout_ctx<<<32768, 128, 0, stream>>>(ctx, ctxb);
  k_cvt_bf16<<<512, 256, 0, stream>>>(Wh, Whb, 4*H_*H_);
  k_cvt_bf16<<<512, 256, 0, stream>>>(Wout, Woutb, H_*2*H_);
  k_cvt_bf16<<<256, 256, 0, stream>>>(Win, Winb, H_*H_);
  k_init_state<<<256, 256, 0, stream>>>(h0, c0, hb, cyb);
  k_zero_bar<<<1, 512, 0, stream>>>(barm);

  // Xg = x @ Wi^T + (bi + bh)   [32768 x 2048], K=512
  k_gemm_bt<1><<<dim3(256,16), 256, 0, stream>>>(x, Wi, Xg, B_*T_, 4*H_, I_, bi, bh);

  // whole recurrence in one persistent kernel
  k_persist<<<256, 512, 0, stream>>>(Xg, ctxb, Whb, Woutb, Winb,
                                     hb, hyb, wcb, targb,
                                     cyb, out, hf, cf,
                                     barm, barm + 256);
}

// Round 3
// 10665.773 us; speedup vs baseline: 1.7892x; 1.7892x over previous
//
#include <hip/hip_runtime.h>
#include <hip/hip_bf16.h>
#include <stdint.h>

#define B_ 128
#define T_ 256
#define S_ 256
#define I_ 512
#define H_ 512
#define RSLOT 32   // ring depth (reuse distance 32 steps)

typedef __attribute__((ext_vector_type(8))) short short8;
typedef __attribute__((ext_vector_type(4))) float f32x4;
typedef unsigned short ushort_t;

__device__ __forceinline__ float bf2f(ushort_t u){
  union{ unsigned int i; float f;} v; v.i = ((unsigned int)u)<<16; return v.f;
}
__device__ __forceinline__ ushort_t f2bf(float f){
  union{ unsigned int i; float f;} v; v.f=f;
  unsigned int x=v.i; unsigned int r = x + 0x7fffu + ((x>>16)&1u);
  return (ushort_t)(r>>16);
}
__device__ __forceinline__ float sigm(float x){ return 1.f/(1.f + __expf(-x)); }
__device__ __forceinline__ float tanh_s(float x){
  float a = fabsf(x);
  float e = __expf(-2.f*a);
  float t = (1.f - e)/(1.f + e);
  return x < 0.f ? -t : t;
}

__device__ __forceinline__ f32x4 MFMA16(short8 a, short8 b, f32x4 c){
  typedef __attribute__((ext_vector_type(8))) __bf16 bf16x8;
  return __builtin_amdgcn_mfma_f32_16x16x32_bf16(
      __builtin_bit_cast(bf16x8, a), __builtin_bit_cast(bf16x8, b), c, 0, 0, 0);
}

// fabric (agent-scope, L1/L2-bypassing) 8B store: visible device-wide w/o fences
__device__ __forceinline__ void fab_store_u64(ushort_t* p, unsigned long long v){
  __hip_atomic_store((unsigned long long*)p, v, __ATOMIC_RELAXED, __HIP_MEMORY_SCOPE_AGENT);
}

// ---------------- converts / init ----------------

__global__ void k_cvt_bf16(const float* __restrict__ src, ushort_t* __restrict__ dst, int n){
  int i = (blockIdx.x*blockDim.x + threadIdx.x)*4;
  int stride = gridDim.x*blockDim.x*4;
  for (; i < n; i += stride){
    float4 v = *(const float4*)(src + i);
    ushort4 o; o.x=f2bf(v.x); o.y=f2bf(v.y); o.z=f2bf(v.z); o.w=f2bf(v.w);
    *(ushort4*)(dst + i) = o;
  }
}

// ctx[s][b][h] f32 -> ctxh[half][b][s][hh] bf16 (split h into two 256-halves)
__global__ void k_relayout_ctx2(const float* __restrict__ ctx, ushort_t* __restrict__ ctxh){
  int s = blockIdx.x >> 7;   // 0..255
  int b = blockIdx.x & 127;  // 0..127
  int tid = threadIdx.x;     // 128 threads
  int h4 = tid*4;
  float4 v = *(const float4*)(ctx + ((size_t)s*128 + b)*512 + h4);
  ushort4 o; o.x=f2bf(v.x); o.y=f2bf(v.y); o.z=f2bf(v.z); o.w=f2bf(v.w);
  int half = tid >> 6, hh = h4 & 255;
  *(ushort4*)(ctxh + (((size_t)half*128 + b)*256 + s)*256 + hh) = o;
}

// out[j*512+k] = in[k*512+j]
__global__ void k_transpose_512(const float* __restrict__ in, float* __restrict__ out){
  __shared__ float tile[32][33];
  int bx = blockIdx.x*32, by = blockIdx.y*32;
  int tx = threadIdx.x, ty = threadIdx.y; // block (32,8)
  for (int r=0;r<32;r+=8) tile[ty+r][tx] = in[(by+ty+r)*512 + bx+tx];
  __syncthreads();
  for (int r=0;r<32;r+=8) out[(bx+ty+r)*512 + by+tx] = tile[tx][ty+r];
}

__global__ void k_init_state(const float* __restrict__ h0, const float* __restrict__ c0,
                             ushort_t* __restrict__ hring0, float* __restrict__ cyb){
  int i = blockIdx.x*blockDim.x + threadIdx.x; // 65536 total
  hring0[i] = f2bf(h0[i]);
  cyb[i] = c0[i];
}

__global__ void k_zero_bar(int* f){
  if (threadIdx.x < 256) f[threadIdx.x] = 0;
}

// ---------------- precompute GEMMs ----------------
// C[M,N] = A[M,K] @ B[N,K]^T (+bias). SWAP=1: out row m -> (m&127)*256 + (m>>7)
template<int BIAS, int SWAP>
__global__ __launch_bounds__(256) void k_gemm_bt(
    const float* __restrict__ A, const float* __restrict__ Bm,
    ushort_t* __restrict__ C, int M, int N, int K,
    const float* __restrict__ bias0, const float* __restrict__ bias1){
  __shared__ ushort_t Asm[128][40];
  __shared__ ushort_t Bsm[128][40];
  const int tid = threadIdx.x;
  const int mBase = blockIdx.x*128, nBase = blockIdx.y*128;
  const int l = tid & 63, wv = tid >> 6;
  const int wm = (wv>>1)*64, wn = (wv&1)*64;
  const int lr = l & 15, lq = l >> 4;
  const int srow = tid >> 1, scol = (tid & 1)*16;
  const float* Ap = A + (size_t)(mBase + srow)*K + scol;
  const float* Bp = Bm + (size_t)(nBase + srow)*K + scol;

  f32x4 acc[4][4];
  #pragma unroll
  for (int i=0;i<4;i++)
    #pragma unroll
    for (int j=0;j<4;j++) acc[i][j] = (f32x4)0.f;

  for (int k0 = 0; k0 < K; k0 += 32){
    float4 a0 = *(const float4*)(Ap + k0);
    float4 a1 = *(const float4*)(Ap + k0 + 4);
    float4 a2 = *(const float4*)(Ap + k0 + 8);
    float4 a3 = *(const float4*)(Ap + k0 + 12);
    float4 b0 = *(const float4*)(Bp + k0);
    float4 b1 = *(const float4*)(Bp + k0 + 4);
    float4 b2 = *(const float4*)(Bp + k0 + 8);
    float4 b3 = *(const float4*)(Bp + k0 + 12);
    __syncthreads();
    {
      ushort4 w;
      w.x=f2bf(a0.x); w.y=f2bf(a0.y); w.z=f2bf(a0.z); w.w=f2bf(a0.w);
      *(ushort4*)&Asm[srow][scol+0]  = w;
      w.x=f2bf(a1.x); w.y=f2bf(a1.y); w.z=f2bf(a1.z); w.w=f2bf(a1.w);
      *(ushort4*)&Asm[srow][scol+4]  = w;
      w.x=f2bf(a2.x); w.y=f2bf(a2.y); w.z=f2bf(a2.z); w.w=f2bf(a2.w);
      *(ushort4*)&Asm[srow][scol+8]  = w;
      w.x=f2bf(a3.x); w.y=f2bf(a3.y); w.z=f2bf(a3.z); w.w=f2bf(a3.w);
      *(ushort4*)&Asm[srow][scol+12] = w;
      w.x=f2bf(b0.x); w.y=f2bf(b0.y); w.z=f2bf(b0.z); w.w=f2bf(b0.w);
      *(ushort4*)&Bsm[srow][scol+0]  = w;
      w.x=f2bf(b1.x); w.y=f2bf(b1.y); w.z=f2bf(b1.z); w.w=f2bf(b1.w);
      *(ushort4*)&Bsm[srow][scol+4]  = w;
      w.x=f2bf(b2.x); w.y=f2bf(b2.y); w.z=f2bf(b2.z); w.w=f2bf(b2.w);
      *(ushort4*)&Bsm[srow][scol+8]  = w;
      w.x=f2bf(b3.x); w.y=f2bf(b3.y); w.z=f2bf(b3.z); w.w=f2bf(b3.w);
      *(ushort4*)&Bsm[srow][scol+12] = w;
    }
    __syncthreads();
    short8 aF[4], bF[4];
    #pragma unroll
    for (int i=0;i<4;i++) aF[i] = *(const short8*)&Asm[wm + i*16 + lr][lq*8];
    #pragma unroll
    for (int j=0;j<4;j++) bF[j] = *(const short8*)&Bsm[wn + j*16 + lr][lq*8];
    #pragma unroll
    for (int i=0;i<4;i++)
      #pragma unroll
      for (int j=0;j<4;j++)
        acc[i][j] = MFMA16(aF[i], bF[j], acc[i][j]);
  }

  #pragma unroll
  for (int j=0;j<4;j++){
    int col = nBase + wn + j*16 + lr;
    float bsum = 0.f;
    if (BIAS) bsum = bias0[col] + bias1[col];
    #pragma unroll
    for (int i=0;i<4;i++){
      int row0 = mBase + wm + i*16 + lq*4;
      #pragma unroll
      for (int r=0;r<4;r++){
        int row = row0 + r;
        size_t drow = SWAP ? ((size_t)(row & 127)*256 + (row >> 7)) : (size_t)row;
        C[drow*N + col] = f2bf(acc[i][j][r] + bsum);
      }
    }
  }
}

// ---------------- fence-free grid barrier (no cache maintenance) ----------------
// __syncthreads drains each wave's vmcnt (incl. fabric stores) before s_barrier,
// so the flag store has release semantics w.r.t. prior fabric data stores.
__device__ __forceinline__ void gbar(int* flags, int gen){
  __syncthreads();
  const int tid = threadIdx.x;
  if (tid == 0)
    __hip_atomic_store(&flags[blockIdx.x], gen, __ATOMIC_RELAXED, __HIP_MEMORY_SCOPE_AGENT);
  if (tid < 256){
    while (__hip_atomic_load(&flags[tid], __ATOMIC_RELAXED, __HIP_MEMORY_SCOPE_AGENT) < gen)
      __builtin_amdgcn_s_sleep(2);
  }
  __syncthreads();
  asm volatile("" ::: "memory");
}

// ---------------- persistent recurrence kernel ----------------
// 256 blocks x 512 threads. Mutable cross-block data flows through depth-32
// rings: written ONLY via fabric atomics (never dirty in any L2), read via
// plain cached loads (address untouched for 32 steps -> no stale lines).

__global__ __launch_bounds__(512, 1) void k_persist(
    const ushort_t* __restrict__ Xg, const ushort_t* __restrict__ C2b,
    const ushort_t* __restrict__ ctxh, const ushort_t* __restrict__ Whb,
    const ushort_t* __restrict__ Woutb,
    ushort_t* hring, ushort_t* hyring, ushort_t* wcring,
    float* cyb, float* out, float* hf, float* cf, int* flags)
{
  __shared__ union ShMem {
    struct { float red[8][256]; ushort_t pk[16][16]; } a;
    struct { float hy[512]; float sc[256]; float p[256]; float inv; float pad;
             float2 accs[512]; unsigned int pk32[128]; } b;
  } sh;

  const int pbid = blockIdx.x;
  const int tid = threadIdx.x;
  const int l = tid & 63, wv = tid >> 6;     // 8 waves
  const int lr = l & 15, lq = l >> 4;
  int gen = 0;

  for (int t = 0; t < T_; ++t){
    const size_t slotC = (size_t)(t & (RSLOT-1)) * 65536;   // current-step rings
    // ======== Phase A: gates = Xg[:,t,:] + h @ Wh^T ; LSTM pointwise -> hy ========
    {
      const int bm = pbid >> 5, hc = pbid & 31;   // 8 b-tiles x 32 h-chunks
      const int gate = wv & 3, khalf = wv >> 2;
      f32x4 acc = (f32x4)0.f;
      const ushort_t* ap = hring + slotC + (bm*16 + lr)*512 + khalf*256 + lq*8;
      const ushort_t* bp = Whb + (size_t)(gate*512 + hc*16 + lr)*512 + khalf*256 + lq*8;
      #pragma unroll
      for (int kk = 0; kk < 8; ++kk){
        short8 aF = *(const short8*)(ap + kk*32);
        short8 bF = *(const short8*)(bp + kk*32);
        acc = MFMA16(aF, bF, acc);
      }
      #pragma unroll
      for (int r = 0; r < 4; ++r) sh.a.red[wv][(lq*4 + r)*16 + lr] = acc[r];
      __syncthreads();
      if (tid < 256){
        const int b = bm*16 + (tid >> 4), h = hc*16 + (tid & 15);
        const ushort_t* xg = Xg + ((size_t)b*T_ + t)*2048 + h;
        float gi  = sh.a.red[0][tid] + sh.a.red[4][tid] + bf2f(xg[0]);
        float gf  = sh.a.red[1][tid] + sh.a.red[5][tid] + bf2f(xg[512]);
        float gg  = sh.a.red[2][tid] + sh.a.red[6][tid] + bf2f(xg[1024]);
        float go_ = sh.a.red[3][tid] + sh.a.red[7][tid] + bf2f(xg[1536]);
        float co = cyb[b*512 + h];
        float cn = sigm(gf)*co + sigm(gi)*tanh_s(gg);
        float hn = sigm(go_)*tanh_s(cn);
        cyb[b*512 + h] = cn;                        // block-local: plain cached
        sh.a.pk[tid >> 4][tid & 15] = f2bf(hn);
        if (t == T_-1) cf[b*512 + h] = cn;
      }
      __syncthreads();
      if (tid < 64){
        int r = tid >> 2, c4 = tid & 3;
        unsigned long long v = *(unsigned long long*)&sh.a.pk[r][c4*4];
        fab_store_u64(hyring + slotC + (bm*16 + r)*512 + hc*16 + c4*4, v);
      }
    }
    gbar(flags, ++gen);

    // ======== Phase B: attention (score via C2, softmax, wc h-half) ========
    {
      const int b = pbid >> 1, half = pbid & 1;   // 2 blocks per batch row
      if (tid < 128){
        ushort4 v = *(const ushort4*)(hyring + slotC + b*512 + tid*4);
        sh.b.hy[tid*4+0] = bf2f(v.x); sh.b.hy[tid*4+1] = bf2f(v.y);
        sh.b.hy[tid*4+2] = bf2f(v.z); sh.b.hy[tid*4+3] = bf2f(v.w);
      }
      __syncthreads();
      // dots: score[s] = hy[b] . C2b[b][s][:]   (all 256 s, redundant per pair)
      {
        float hv[8];
        #pragma unroll
        for (int e = 0; e < 8; ++e) hv[e] = sh.b.hy[l*8 + e];
        const ushort_t* c2p = C2b + (size_t)b*131072;
        #pragma unroll 2
        for (int i = 0; i < 32; ++i){
          int s = wv*32 + i;
          short8 cv = *(const short8*)(c2p + (size_t)s*512 + l*8);
          float d = 0.f;
          #pragma unroll
          for (int e = 0; e < 8; ++e) d += bf2f((ushort_t)cv[e]) * hv[e];
          #pragma unroll
          for (int off = 32; off; off >>= 1) d += __shfl_xor(d, off);
          if (l == 0) sh.b.sc[s] = d;
        }
      }
      __syncthreads();
      if (wv == 0){
        float v0 = sh.b.sc[l], v1 = sh.b.sc[l+64], v2 = sh.b.sc[l+128], v3 = sh.b.sc[l+192];
        float m = fmaxf(fmaxf(v0,v1), fmaxf(v2,v3));
        #pragma unroll
        for (int off = 32; off; off >>= 1) m = fmaxf(m, __shfl_xor(m, off));
        float e0=__expf(v0-m), e1=__expf(v1-m), e2=__expf(v2-m), e3=__expf(v3-m);
        float s4 = (e0+e1)+(e2+e3);
        #pragma unroll
        for (int off = 32; off; off >>= 1) s4 += __shfl_xor(s4, off);
        sh.b.p[l]=e0; sh.b.p[l+64]=e1; sh.b.p[l+128]=e2; sh.b.p[l+192]=e3;
        if (l == 0) sh.b.inv = 1.f/s4;
      }
      __syncthreads();
      // wc[b, half] = sum_s p[s] * ctxh[half][b][s][:]
      {
        const int hp = tid & 127, sq = tid >> 7;
        const ushort_t* cxp = ctxh + (((size_t)half*128 + b)*256)*256;
        float2 a2 = make_float2(0.f, 0.f);
        #pragma unroll 4
        for (int j = 0; j < 64; ++j){
          int s = sq*64 + j;
          unsigned int uv = *(const unsigned int*)(cxp + (size_t)s*256 + hp*2);
          float pw = sh.b.p[s];
          a2.x += pw * bf2f((ushort_t)(uv & 0xffffu));
          a2.y += pw * bf2f((ushort_t)(uv >> 16));
        }
        sh.b.accs[tid] = a2;
      }
      __syncthreads();
      if (tid < 128){
        float inv = sh.b.inv;
        float2 a0 = sh.b.accs[tid],       a1 = sh.b.accs[tid + 128];
        float2 a2 = sh.b.accs[tid + 256], a3 = sh.b.accs[tid + 384];
        float x = (a0.x + a1.x + a2.x + a3.x)*inv;
        float y = (a0.y + a1.y + a2.y + a3.y)*inv;
        sh.b.pk32[tid] = (unsigned)f2bf(x) | ((unsigned)f2bf(y) << 16);
      }
      __syncthreads();
      if (tid < 64){
        unsigned long long v = *(unsigned long long*)&sh.b.pk32[tid*2];
        fab_store_u64(wcring + slotC + b*512 + half*256 + tid*4, v);
      }
    }
    gbar(flags, ++gen);

    // ======== Phase C: h_tilde = tanh([wc|hy] @ W_out^T) ========
    {
      const int bm = pbid >> 5, nc = pbid & 31;
      f32x4 acc = (f32x4)0.f;
      const ushort_t* ap = (wv < 4 ? wcring : hyring) + slotC
                           + (bm*16 + lr)*512 + (wv & 3)*128 + lq*8;
      const ushort_t* bp = Woutb + (size_t)(nc*16 + lr)*1024 + wv*128 + lq*8;
      #pragma unroll
      for (int kk = 0; kk < 4; ++kk){
        short8 aF = *(const short8*)(ap + kk*32);
        short8 bF = *(const short8*)(bp + kk*32);
        acc = MFMA16(aF, bF, acc);
      }
      #pragma unroll
      for (int r = 0; r < 4; ++r) sh.a.red[wv][(lq*4 + r)*16 + lr] = acc[r];
      __syncthreads();
      if (tid < 256){
        float s = 0.f;
        #pragma unroll
        for (int w = 0; w < 8; ++w) s += sh.a.red[w][tid];
        float v = tanh_s(s);
        const int b = bm*16 + (tid >> 4), n = nc*16 + (tid & 15);
        out[((size_t)b*T_ + t)*512 + n] = v;
        sh.a.pk[tid >> 4][tid & 15] = f2bf(v);
        if (t == T_-1) hf[b*512 + n] = v;
      }
      __syncthreads();
      if (tid < 64){
        int r = tid >> 2, c4 = tid & 3;
        unsigned long long v = *(unsigned long long*)&sh.a.pk[r][c4*4];
        size_t slotN = (size_t)((t+1) & (RSLOT-1)) * 65536;
        fab_store_u64(hring + slotN + (bm*16 + r)*512 + nc*16 + c4*4, v);
      }
    }
    gbar(flags, ++gen);
  }
}

// ---------------- host ----------------

extern "C" void kernel_launch(void* const* d_in, const int* in_sizes, int n_in,
                              void* d_out, int out_size, void* d_ws, size_t ws_size,
                              hipStream_t stream){
  const float* x    = (const float*)d_in[0];
  const float* h0   = (const float*)d_in[1];
  const float* c0   = (const float*)d_in[2];
  const float* ctx  = (const float*)d_in[3];
  const float* Wi   = (const float*)d_in[4];
  const float* bi   = (const float*)d_in[5];
  const float* Wh   = (const float*)d_in[6];
  const float* bh   = (const float*)d_in[7];
  const float* Win  = (const float*)d_in[8];
  const float* Wout = (const float*)d_in[9];

  char* ws = (char*)d_ws;
  ushort_t* Xg     = (ushort_t*)(ws);                 // 134217728
  ushort_t* C2b    = (ushort_t*)(ws + 134217728);     //  33554432  [b][s][512]
  ushort_t* ctxh   = (ushort_t*)(ws + 167772160);     //  33554432  [2][b][s][256]
  ushort_t* Whb    = (ushort_t*)(ws + 201326592);     //   2097152
  ushort_t* Woutb  = (ushort_t*)(ws + 203423744);     //   1048576
  float*    WinT   = (float*)   (ws + 204472320);     //   1048576
  ushort_t* hyring = (ushort_t*)(ws + 205520896);     //   4194304
  ushort_t* wcring = (ushort_t*)(ws + 209715200);     //   4194304
  ushort_t* hring  = (ushort_t*)(ws + 213909504);     //   4194304
  float*    cyb    = (float*)   (ws + 218103808);     //    262144
  int*      flags  = (int*)     (ws + 218365952);     //      1024

  float* out = (float*)d_out;
  float* hf  = out + (size_t)B_*T_*H_;
  float* cf  = hf + (size_t)B_*H_;

  // precompute / converts
  k_relayout_ctx2<<<32768, 128, 0, stream>>>(ctx, ctxh);
  k_cvt_bf16<<<512, 256, 0, stream>>>(Wh, Whb, 4*H_*H_);
  k_cvt_bf16<<<512, 256, 0, stream>>>(Wout, Woutb, H_*2*H_);
  k_transpose_512<<<dim3(16,16), dim3(32,8), 0, stream>>>(Win, WinT);
  k_init_state<<<256, 256, 0, stream>>>(h0, c0, hring, cyb);
  k_zero_bar<<<1, 256, 0, stream>>>(flags);

  // Xg = x @ Wi^T + (bi + bh)   [32768 x 2048], K=512
  k_gemm_bt<1,0><<<dim3(256,16), 256, 0, stream>>>(x, Wi, Xg, B_*T_, 4*H_, I_, bi, bh);
  // C2b[b][s][:] = ctx[s][b][:] @ W_in  (B-matrix = Win^T in [N,K] form), swapped rows
  k_gemm_bt<0,1><<<dim3(256,4), 256, 0, stream>>>(ctx, WinT, C2b, S_*B_, H_, H_, nullptr, nullptr);

  // whole recurrence, fence-free persistent kernel
  k_persist<<<256, 512, 0, stream>>>(Xg, C2b, ctxh, Whb, Woutb,
                                     hring, hyring, wcring,
                                     cyb, out, hf, cf, flags);
}

// Round 4
// 9043.744 us; speedup vs baseline: 2.1100x; 1.1794x over previous
//
#include <hip/hip_runtime.h>
#include <hip/hip_bf16.h>
#include <stdint.h>

#define B_ 128
#define T_ 256
#define S_ 256
#define I_ 512
#define H_ 512
#define RSLOT 32   // ring depth (reuse distance 32 steps)

typedef __attribute__((ext_vector_type(8))) short short8;
typedef __attribute__((ext_vector_type(4))) float f32x4;
typedef unsigned short ushort_t;

__device__ __forceinline__ float bf2f(ushort_t u){
  union{ unsigned int i; float f;} v; v.i = ((unsigned int)u)<<16; return v.f;
}
__device__ __forceinline__ ushort_t f2bf(float f){
  union{ unsigned int i; float f;} v; v.f=f;
  unsigned int x=v.i; unsigned int r = x + 0x7fffu + ((x>>16)&1u);
  return (ushort_t)(r>>16);
}
__device__ __forceinline__ float sigm(float x){ return 1.f/(1.f + __expf(-x)); }
__device__ __forceinline__ float tanh_s(float x){
  float a = fabsf(x);
  float e = __expf(-2.f*a);
  float t = (1.f - e)/(1.f + e);
  return x < 0.f ? -t : t;
}

__device__ __forceinline__ f32x4 MFMA16(short8 a, short8 b, f32x4 c){
  typedef __attribute__((ext_vector_type(8))) __bf16 bf16x8;
  return __builtin_amdgcn_mfma_f32_16x16x32_bf16(
      __builtin_bit_cast(bf16x8, a), __builtin_bit_cast(bf16x8, b), c, 0, 0, 0);
}

// fabric (agent-scope) 8B store: visible device-wide w/o cache maintenance
__device__ __forceinline__ void fab_store_u64(ushort_t* p, unsigned long long v){
  __hip_atomic_store((unsigned long long*)p, v, __ATOMIC_RELAXED, __HIP_MEMORY_SCOPE_AGENT);
}

// ---------------- converts / init ----------------

__global__ void k_cvt_bf16(const float* __restrict__ src, ushort_t* __restrict__ dst, int n){
  int i = (blockIdx.x*blockDim.x + threadIdx.x)*4;
  int stride = gridDim.x*blockDim.x*4;
  for (; i < n; i += stride){
    float4 v = *(const float4*)(src + i);
    ushort4 o; o.x=f2bf(v.x); o.y=f2bf(v.y); o.z=f2bf(v.z); o.w=f2bf(v.w);
    *(ushort4*)(dst + i) = o;
  }
}

// ctx[s][b][h] f32 -> ctxb[b][s][h] bf16
__global__ void k_relayout_ctx(const float* __restrict__ ctx, ushort_t* __restrict__ ctxb){
  int s = blockIdx.x >> 7;   // 0..255
  int b = blockIdx.x & 127;  // 0..127
  int h4 = threadIdx.x * 4;  // 128 threads
  float4 v = *(const float4*)(ctx + ((size_t)s*128 + b)*512 + h4);
  ushort4 o; o.x=f2bf(v.x); o.y=f2bf(v.y); o.z=f2bf(v.z); o.w=f2bf(v.w);
  *(ushort4*)(ctxb + ((size_t)b*256 + s)*512 + h4) = o;
}

// out[j*512+k] = in[k*512+j]
__global__ void k_transpose_512(const float* __restrict__ in, float* __restrict__ out){
  __shared__ float tile[32][33];
  int bx = blockIdx.x*32, by = blockIdx.y*32;
  int tx = threadIdx.x, ty = threadIdx.y; // block (32,8)
  for (int r=0;r<32;r+=8) tile[ty+r][tx] = in[(by+ty+r)*512 + bx+tx];
  __syncthreads();
  for (int r=0;r<32;r+=8) out[(bx+ty+r)*512 + by+tx] = tile[tx][ty+r];
}

__global__ void k_init_state(const float* __restrict__ h0, const float* __restrict__ c0,
                             ushort_t* __restrict__ hring0, float* __restrict__ cyb){
  int i = blockIdx.x*blockDim.x + threadIdx.x; // 65536 total
  hring0[i] = f2bf(h0[i]);
  cyb[i] = c0[i];
}

__global__ void k_zero_bar(int* f){
  if (threadIdx.x < 256) f[threadIdx.x] = 0;
}

// ---------------- precompute GEMMs ----------------
// C[M,N] = A[M,K] @ B[N,K]^T (+bias). SWAP=1: out row m -> (m&127)*256 + (m>>7)
template<int BIAS, int SWAP>
__global__ __launch_bounds__(256) void k_gemm_bt(
    const float* __restrict__ A, const float* __restrict__ Bm,
    ushort_t* __restrict__ C, int M, int N, int K,
    const float* __restrict__ bias0, const float* __restrict__ bias1){
  __shared__ ushort_t Asm[128][40];
  __shared__ ushort_t Bsm[128][40];
  const int tid = threadIdx.x;
  const int mBase = blockIdx.x*128, nBase = blockIdx.y*128;
  const int l = tid & 63, wv = tid >> 6;
  const int wm = (wv>>1)*64, wn = (wv&1)*64;
  const int lr = l & 15, lq = l >> 4;
  const int srow = tid >> 1, scol = (tid & 1)*16;
  const float* Ap = A + (size_t)(mBase + srow)*K + scol;
  const float* Bp = Bm + (size_t)(nBase + srow)*K + scol;

  f32x4 acc[4][4];
  #pragma unroll
  for (int i=0;i<4;i++)
    #pragma unroll
    for (int j=0;j<4;j++) acc[i][j] = (f32x4)0.f;

  for (int k0 = 0; k0 < K; k0 += 32){
    float4 a0 = *(const float4*)(Ap + k0);
    float4 a1 = *(const float4*)(Ap + k0 + 4);
    float4 a2 = *(const float4*)(Ap + k0 + 8);
    float4 a3 = *(const float4*)(Ap + k0 + 12);
    float4 b0 = *(const float4*)(Bp + k0);
    float4 b1 = *(const float4*)(Bp + k0 + 4);
    float4 b2 = *(const float4*)(Bp + k0 + 8);
    float4 b3 = *(const float4*)(Bp + k0 + 12);
    __syncthreads();
    {
      ushort4 w;
      w.x=f2bf(a0.x); w.y=f2bf(a0.y); w.z=f2bf(a0.z); w.w=f2bf(a0.w);
      *(ushort4*)&Asm[srow][scol+0]  = w;
      w.x=f2bf(a1.x); w.y=f2bf(a1.y); w.z=f2bf(a1.z); w.w=f2bf(a1.w);
      *(ushort4*)&Asm[srow][scol+4]  = w;
      w.x=f2bf(a2.x); w.y=f2bf(a2.y); w.z=f2bf(a2.z); w.w=f2bf(a2.w);
      *(ushort4*)&Asm[srow][scol+8]  = w;
      w.x=f2bf(a3.x); w.y=f2bf(a3.y); w.z=f2bf(a3.z); w.w=f2bf(a3.w);
      *(ushort4*)&Asm[srow][scol+12] = w;
      w.x=f2bf(b0.x); w.y=f2bf(b0.y); w.z=f2bf(b0.z); w.w=f2bf(b0.w);
      *(ushort4*)&Bsm[srow][scol+0]  = w;
      w.x=f2bf(b1.x); w.y=f2bf(b1.y); w.z=f2bf(b1.z); w.w=f2bf(b1.w);
      *(ushort4*)&Bsm[srow][scol+4]  = w;
      w.x=f2bf(b2.x); w.y=f2bf(b2.y); w.z=f2bf(b2.z); w.w=f2bf(b2.w);
      *(ushort4*)&Bsm[srow][scol+8]  = w;
      w.x=f2bf(b3.x); w.y=f2bf(b3.y); w.z=f2bf(b3.z); w.w=f2bf(b3.w);
      *(ushort4*)&Bsm[srow][scol+12] = w;
    }
    __syncthreads();
    short8 aF[4], bF[4];
    #pragma unroll
    for (int i=0;i<4;i++) aF[i] = *(const short8*)&Asm[wm + i*16 + lr][lq*8];
    #pragma unroll
    for (int j=0;j<4;j++) bF[j] = *(const short8*)&Bsm[wn + j*16 + lr][lq*8];
    #pragma unroll
    for (int i=0;i<4;i++)
      #pragma unroll
      for (int j=0;j<4;j++)
        acc[i][j] = MFMA16(aF[i], bF[j], acc[i][j]);
  }

  #pragma unroll
  for (int j=0;j<4;j++){
    int col = nBase + wn + j*16 + lr;
    float bsum = 0.f;
    if (BIAS) bsum = bias0[col] + bias1[col];
    #pragma unroll
    for (int i=0;i<4;i++){
      int row0 = mBase + wm + i*16 + lq*4;
      #pragma unroll
      for (int r=0;r<4;r++){
        int row = row0 + r;
        size_t drow = SWAP ? ((size_t)(row & 127)*256 + (row >> 7)) : (size_t)row;
        C[drow*N + col] = f2bf(acc[i][j][r] + bsum);
      }
    }
  }
}

// ---------------- fence-free grid barrier ----------------
__device__ __forceinline__ void gbar(int* flags, int gen){
  __syncthreads();
  const int tid = threadIdx.x;
  if (tid == 0)
    __hip_atomic_store(&flags[blockIdx.x], gen, __ATOMIC_RELAXED, __HIP_MEMORY_SCOPE_AGENT);
  if (tid < 256){
    while (__hip_atomic_load(&flags[tid], __ATOMIC_RELAXED, __HIP_MEMORY_SCOPE_AGENT) < gen)
      __builtin_amdgcn_s_sleep(2);
  }
  __syncthreads();
  asm volatile("" ::: "memory");
}

// ---------------- persistent recurrence kernel ----------------
// 256 blocks x 512 threads. Weights live in registers for the whole kernel;
// cross-block state flows through depth-32 rings (fabric stores / cached reads).

__global__ __launch_bounds__(512) void k_persist(
    const ushort_t* __restrict__ Xg, const ushort_t* __restrict__ C2b,
    const ushort_t* __restrict__ ctxb, const ushort_t* __restrict__ Whb,
    const ushort_t* __restrict__ Woutb,
    ushort_t* hring, ushort_t* hyring, ushort_t* wcring,
    float* cyb, float* out, float* hf, float* cf, int* flags)
{
  __shared__ union {
    struct { float red[8][256]; ushort_t pk[256]; } a;
    struct { float sc[256]; float p[256]; float inv;
             float pacc[16][256]; ushort_t pk[256]; } b;
  } sh;

  const int pbid = blockIdx.x;
  const int tid = threadIdx.x;
  const int l = tid & 63, wv = tid >> 6;     // 8 waves
  const int lr = l & 15, lq = l >> 4;

  // ---- pin weight fragments in registers for the whole kernel ----
  const int bm = pbid >> 5, hc = pbid & 31;       // phase A / C tiles
  const int gate = wv & 3, khalf = wv >> 2;
  short8 whr[8];
  #pragma unroll
  for (int kk=0;kk<8;kk++)
    whr[kk] = *(const short8*)(Whb + (size_t)(gate*512 + hc*16 + lr)*512
                               + khalf*256 + lq*8 + kk*32);
  short8 wor[4];
  #pragma unroll
  for (int kk=0;kk<4;kk++)
    wor[kk] = *(const short8*)(Woutb + (size_t)(hc*16 + lr)*1024
                               + wv*128 + lq*8 + kk*32);

  const int bB = pbid >> 1, half = pbid & 1;      // phase B ids

  int gen = 0;
  for (int t = 0; t < T_; ++t){
    const size_t slotC = (size_t)(t & (RSLOT-1)) * 65536;

    // ======== Phase A: gates = Xg[:,t,:] + h @ Wh^T ; LSTM pointwise ========
    {
      f32x4 acc = (f32x4)0.f;
      const ushort_t* ap = hring + slotC + (size_t)(bm*16 + lr)*512 + khalf*256 + lq*8;
      short8 hv8[8];
      #pragma unroll
      for (int kk=0;kk<8;kk++) hv8[kk] = *(const short8*)(ap + kk*32);
      #pragma unroll
      for (int kk=0;kk<8;kk++) acc = MFMA16(hv8[kk], whr[kk], acc);
      #pragma unroll
      for (int r=0;r<4;r++) sh.a.red[wv][(lq*4+r)*16+lr] = acc[r];
      __syncthreads();
      if (tid < 256){
        const int b = bm*16 + (tid>>4), h = hc*16 + (tid&15);
        const ushort_t* xg = Xg + ((size_t)b*T_ + t)*2048 + h;
        float gi  = sh.a.red[0][tid] + sh.a.red[4][tid] + bf2f(xg[0]);
        float gf  = sh.a.red[1][tid] + sh.a.red[5][tid] + bf2f(xg[512]);
        float gg  = sh.a.red[2][tid] + sh.a.red[6][tid] + bf2f(xg[1024]);
        float go_ = sh.a.red[3][tid] + sh.a.red[7][tid] + bf2f(xg[1536]);
        float co = cyb[b*512 + h];
        float cn = sigm(gf)*co + sigm(gi)*tanh_s(gg);
        float hn = sigm(go_)*tanh_s(cn);
        cyb[b*512 + h] = cn;                        // block-local: plain cached
        sh.a.pk[tid] = f2bf(hn);
        if (t == T_-1) cf[b*512 + h] = cn;
      }
      __syncthreads();
      if (tid < 64){
        unsigned long long v = *(unsigned long long*)&sh.a.pk[tid*4];
        fab_store_u64(hyring + slotC + (size_t)(bm*16 + (tid>>2))*512
                      + hc*16 + (tid&3)*4, v);
      }
    }
    gbar(flags, ++gen);

    // ======== Phase B: attention (scores via C2, softmax, wc half) ========
    {
      float hv[8];
      {
        short8 hvv = *(const short8*)(hyring + slotC + (size_t)bB*512 + l*8);
        #pragma unroll
        for (int e=0;e<8;e++) hv[e] = bf2f((ushort_t)hvv[e]);
      }
      // scores: wave wv owns s in [wv*32, wv*32+32), 8-deep double-buffered
      {
        const ushort_t* c2p = C2b + (size_t)bB*131072 + (size_t)(wv*32)*512 + l*8;
        short8 ca[8], cb[8];
        #pragma unroll
        for (int j=0;j<8;j++) ca[j] = *(const short8*)(c2p + (size_t)j*512);
        #pragma unroll
        for (int c=0;c<4;c++){
          if (c<3){
            #pragma unroll
            for (int j=0;j<8;j++){
              short8 v = *(const short8*)(c2p + (size_t)((c+1)*8+j)*512);
              if (c&1) ca[j]=v; else cb[j]=v;
            }
          }
          #pragma unroll
          for (int j=0;j<8;j++){
            short8 cv = (c&1)? cb[j] : ca[j];
            float d = 0.f;
            #pragma unroll
            for (int e=0;e<8;e++) d += bf2f((ushort_t)cv[e]) * hv[e];
            #pragma unroll
            for (int off=32; off; off>>=1) d += __shfl_xor(d, off);
            if (l==0) sh.b.sc[wv*32 + c*8 + j] = d;
          }
        }
      }
      __syncthreads();
      if (wv == 0){
        float v0=sh.b.sc[l], v1=sh.b.sc[l+64], v2=sh.b.sc[l+128], v3=sh.b.sc[l+192];
        float m = fmaxf(fmaxf(v0,v1), fmaxf(v2,v3));
        #pragma unroll
        for (int off=32; off; off>>=1) m = fmaxf(m, __shfl_xor(m, off));
        float e0=__expf(v0-m), e1=__expf(v1-m), e2=__expf(v2-m), e3=__expf(v3-m);
        float s4 = (e0+e1)+(e2+e3);
        #pragma unroll
        for (int off=32; off; off>>=1) s4 += __shfl_xor(s4, off);
        sh.b.p[l]=e0; sh.b.p[l+64]=e1; sh.b.p[l+128]=e2; sh.b.p[l+192]=e3;
        if (l==0) sh.b.inv = 1.f/s4;
      }
      __syncthreads();
      // wc: thread = (h-group g of 32, s-strip p of 16), 16B loads, all in flight
      {
        const int g = tid & 31, p = tid >> 5;
        const ushort_t* cxp = ctxb + ((size_t)bB*256 + p*16)*512 + half*256 + g*8;
        short8 va[8], vb[8];
        #pragma unroll
        for (int j=0;j<8;j++) va[j] = *(const short8*)(cxp + (size_t)j*512);
        #pragma unroll
        for (int j=0;j<8;j++) vb[j] = *(const short8*)(cxp + (size_t)(8+j)*512);
        float a8[8];
        #pragma unroll
        for (int e=0;e<8;e++) a8[e]=0.f;
        #pragma unroll
        for (int j=0;j<8;j++){
          float pw = sh.b.p[p*16 + j];
          #pragma unroll
          for (int e=0;e<8;e++) a8[e] += pw * bf2f((ushort_t)va[j][e]);
        }
        #pragma unroll
        for (int j=0;j<8;j++){
          float pw = sh.b.p[p*16 + 8 + j];
          #pragma unroll
          for (int e=0;e<8;e++) a8[e] += pw * bf2f((ushort_t)vb[j][e]);
        }
        #pragma unroll
        for (int e=0;e<8;e++) sh.b.pacc[p][g*8+e] = a8[e];
      }
      __syncthreads();
      if (tid < 256){
        float s = 0.f;
        #pragma unroll
        for (int p2=0;p2<16;p2++) s += sh.b.pacc[p2][tid];
        sh.b.pk[tid] = f2bf(s * sh.b.inv);
      }
      __syncthreads();
      if (tid < 64){
        unsigned long long v = *(unsigned long long*)&sh.b.pk[tid*4];
        fab_store_u64(wcring + slotC + (size_t)bB*512 + half*256 + tid*4, v);
      }
    }
    gbar(flags, ++gen);

    // ======== Phase C: h_tilde = tanh([wc|hy] @ W_out^T) ========
    {
      f32x4 acc = (f32x4)0.f;
      const ushort_t* ap = (wv < 4 ? wcring : hyring) + slotC
                           + (size_t)(bm*16 + lr)*512 + (wv&3)*128 + lq*8;
      short8 av[4];
      #pragma unroll
      for (int kk=0;kk<4;kk++) av[kk] = *(const short8*)(ap + kk*32);
      #pragma unroll
      for (int kk=0;kk<4;kk++) acc = MFMA16(av[kk], wor[kk], acc);
      #pragma unroll
      for (int r=0;r<4;r++) sh.a.red[wv][(lq*4+r)*16+lr] = acc[r];
      __syncthreads();
      if (tid < 256){
        float s = 0.f;
        #pragma unroll
        for (int w=0;w<8;w++) s += sh.a.red[w][tid];
        float v = tanh_s(s);
        const int b = bm*16 + (tid>>4), n = hc*16 + (tid&15);
        out[((size_t)b*T_ + t)*512 + n] = v;
        sh.a.pk[tid] = f2bf(v);
        if (t == T_-1) hf[b*512 + n] = v;
      }
      __syncthreads();
      if (tid < 64){
        unsigned long long v = *(unsigned long long*)&sh.a.pk[tid*4];
        size_t slotN = (size_t)((t+1) & (RSLOT-1)) * 65536;
        fab_store_u64(hring + slotN + (size_t)(bm*16 + (tid>>2))*512
                      + hc*16 + (tid&3)*4, v);
      }
    }
    gbar(flags, ++gen);
  }
}

// ---------------- host ----------------

extern "C" void kernel_launch(void* const* d_in, const int* in_sizes, int n_in,
                              void* d_out, int out_size, void* d_ws, size_t ws_size,
                              hipStream_t stream){
  const float* x    = (const float*)d_in[0];
  const float* h0   = (const float*)d_in[1];
  const float* c0   = (const float*)d_in[2];
  const float* ctx  = (const float*)d_in[3];
  const float* Wi   = (const float*)d_in[4];
  const float* bi   = (const float*)d_in[5];
  const float* Wh   = (const float*)d_in[6];
  const float* bh   = (const float*)d_in[7];
  const float* Win  = (const float*)d_in[8];
  const float* Wout = (const float*)d_in[9];

  char* ws = (char*)d_ws;
  ushort_t* Xg     = (ushort_t*)(ws);                 // 134217728
  ushort_t* C2b    = (ushort_t*)(ws + 134217728);     //  33554432  [b][s][512]
  ushort_t* ctxb   = (ushort_t*)(ws + 167772160);     //  33554432  [b][s][512]
  ushort_t* Whb    = (ushort_t*)(ws + 201326592);     //   2097152
  ushort_t* Woutb  = (ushort_t*)(ws + 203423744);     //   1048576
  float*    WinT   = (float*)   (ws + 204472320);     //   1048576
  ushort_t* hring  = (ushort_t*)(ws + 205520896);     //   4194304
  ushort_t* hyring = (ushort_t*)(ws + 209715200);     //   4194304
  ushort_t* wcring = (ushort_t*)(ws + 213909504);     //   4194304
  float*    cyb    = (float*)   (ws + 218103808);     //    262144
  int*      flags  = (int*)     (ws + 218365952);     //      1024

  float* out = (float*)d_out;
  float* hf  = out + (size_t)B_*T_*H_;
  float* cf  = hf + (size_t)B_*H_;

  // precompute / converts
  k_relayout_ctx<<<32768, 128, 0, stream>>>(ctx, ctxb);
  k_cvt_bf16<<<512, 256, 0, stream>>>(Wh, Whb, 4*H_*H_);
  k_cvt_bf16<<<512, 256, 0, stream>>>(Wout, Woutb, H_*2*H_);
  k_transpose_512<<<dim3(16,16), dim3(32,8), 0, stream>>>(Win, WinT);
  k_init_state<<<256, 256, 0, stream>>>(h0, c0, hring, cyb);
  k_zero_bar<<<1, 256, 0, stream>>>(flags);

  // Xg = x @ Wi^T + (bi + bh)   [32768 x 2048], K=512
  k_gemm_bt<1,0><<<dim3(256,16), 256, 0, stream>>>(x, Wi, Xg, B_*T_, 4*H_, I_, bi, bh);
  // C2b[b][s][:] = ctx[s][b][:] @ W_in  (B-matrix = Win^T in [N,K] form), swapped rows
  k_gemm_bt<0,1><<<dim3(256,4), 256, 0, stream>>>(ctx, WinT, C2b, S_*B_, H_, H_, nullptr, nullptr);

  // whole recurrence, fence-free persistent kernel
  k_persist<<<256, 512, 0, stream>>>(Xg, C2b, ctxb, Whb, Woutb,
                                     hring, hyring, wcring,
                                     cyb, out, hf, cf, flags);
}